// Round 3
// baseline (92.879 us; speedup 1.0000x reference)
//
#include <hip/hip_runtime.h>
#include <hip/hip_bf16.h>

typedef __bf16 bf16x8 __attribute__((ext_vector_type(8)));
typedef float  f32x4  __attribute__((ext_vector_type(4)));
typedef unsigned short us4 __attribute__((ext_vector_type(4)));

#define MFMA16(a, b, c) __builtin_amdgcn_mfma_f32_16x16x32_bf16((a), (b), (c), 0, 0, 0)

constexpr int JJ      = 24;
constexpr int CC      = 64;
constexpr int ROW     = JJ * CC;   // 1536
constexpr int WAVES   = 8;         // 512 threads/block
constexpr int BPW     = 2;         // batches per wave
constexpr int BLOCKS  = 16384 / (WAVES * BPW);  // 1024

__global__ __launch_bounds__(512, 4) void n2e_kernel(
    const float* __restrict__ node, const float* __restrict__ edge,
    const float* __restrict__ adj,
    const float* __restrict__ Wp, const float* __restrict__ bp,
    const float* __restrict__ Wr, const float* __restrict__ br,
    const float* __restrict__ Wc, const float* __restrict__ bc,
    float* __restrict__ out)
{
    __shared__ __bf16 sWc[2 * 64 * 32];
    __shared__ __bf16 sWr[2 * 64 * 32];
    __shared__ __bf16 sWp[2 * 64 * 32];
    __shared__ float  sBsum[64];
    __shared__ float  sBpar[64];
    __shared__ __bf16 sPT[WAVES * 64 * 32];   // per-wave P^T[d][k]

    const int tid = threadIdx.x;

    // ---- stage weights transposed+k-blocked: sW[(c/32)*2048 + d*32 + c%32] = W[c][d] ----
    for (int idx = tid; idx < 4096; idx += 512) {
        int c = idx >> 6, d = idx & 63;
        int dst = (c >> 5) * 2048 + d * 32 + (c & 31);
        sWc[dst] = (__bf16)Wc[idx];
        sWr[dst] = (__bf16)Wr[idx];
        sWp[dst] = (__bf16)Wp[idx];
    }
    if (tid < 64) { sBsum[tid] = bc[tid] + br[tid]; sBpar[tid] = bp[tid]; }
    __syncthreads();   // the ONLY block-wide barrier

    const int lane = tid & 63;
    const int wave = tid >> 6;
    const int r    = lane & 15;    // frag row/col index
    const int g    = lane >> 4;    // k-group

    __bf16* myPT = sPT + wave * 2048;

    float bs[4], bpv[4];
    #pragma unroll
    for (int nt = 0; nt < 4; ++nt) { bs[nt] = sBsum[nt * 16 + r]; bpv[nt] = sBpar[nt * 16 + r]; }

    // safe duplicate row for the j>=24 tail (finite data; results masked downstream)
    const int row1s = (16 + r < JJ) ? (16 + r) : r;
    const bool adjval = (g < 3);   // k-groups 0..2 real, g==3 is the zero pad

    for (int it = 0; it < BPW; ++it) {
        const int b = blockIdx.x * (WAVES * BPW) + wave * BPW + it;
        const float* nf = node + (size_t)b * ROW;
        const float* ef = edge + (size_t)b * ROW;
        const float* af = adj  + (size_t)b * (JJ * JJ);

        // ================= phase 1: issue ALL global loads (raw fp32) =================
        f32x4 rawN[2][2][2], rawE[2][2][2];   // [mt][ks][half]
        #pragma unroll
        for (int mt = 0; mt < 2; ++mt) {
            const int rw = (mt == 0) ? r : row1s;
            const float* np = nf + rw * CC + g * 8;
            const float* ep = ef + rw * CC + g * 8;
            #pragma unroll
            for (int ks = 0; ks < 2; ++ks)
                #pragma unroll
                for (int h = 0; h < 2; ++h) {
                    rawN[mt][ks][h] = *(const f32x4*)(np + ks * 32 + h * 4);
                    rawE[mt][ks][h] = *(const f32x4*)(ep + ks * 32 + h * 4);
                }
        }
        float rawA[2][8];                      // adjT gather: adj[k][j], k=g*8+e, j=mt*16+r
        #pragma unroll
        for (int mt = 0; mt < 2; ++mt) {
            const int j = mt * 16 + r;
            const bool v = adjval && (j < JJ);
            #pragma unroll
            for (int e = 0; e < 8; ++e) {
                const int idx = v ? ((g * 8 + e) * JJ + j) : 0;
                rawA[mt][e] = af[idx];
            }
        }
        __builtin_amdgcn_sched_barrier(0);     // pin: all loads issued before any consumption

        // ================= phase 2: convert to MFMA fragments =================
        bf16x8 aN[2][2], aE[2][2];
        #pragma unroll
        for (int mt = 0; mt < 2; ++mt)
            #pragma unroll
            for (int ks = 0; ks < 2; ++ks) {
                bf16x8 an, ae;
                #pragma unroll
                for (int e = 0; e < 8; ++e) {
                    an[e] = (__bf16)rawN[mt][ks][e >> 2][e & 3];
                    ae[e] = (__bf16)rawE[mt][ks][e >> 2][e & 3];
                }
                aN[mt][ks] = an; aE[mt][ks] = ae;
            }
        bf16x8 aA[2];
        #pragma unroll
        for (int mt = 0; mt < 2; ++mt) {
            const int j = mt * 16 + r;
            const float m = (adjval && (j < JJ)) ? 1.0f : 0.0f;  // aA is the multiplier: must be 0 in pads
            bf16x8 t;
            #pragma unroll
            for (int e = 0; e < 8; ++e) t[e] = (__bf16)(rawA[mt][e] * m);
            aA[mt] = t;
        }

        // ---- children + recurrent: accCR[j-tile][d-tile] ----
        f32x4 accCR[2][4];
        #pragma unroll
        for (int mt = 0; mt < 2; ++mt)
            #pragma unroll
            for (int nt = 0; nt < 4; ++nt) accCR[mt][nt] = f32x4{0.f, 0.f, 0.f, 0.f};
        #pragma unroll
        for (int ks = 0; ks < 2; ++ks) {
            #pragma unroll
            for (int nt = 0; nt < 4; ++nt) {
                bf16x8 bC = *(const bf16x8*)(sWc + ks * 2048 + (nt * 16 + r) * 32 + g * 8);
                bf16x8 bR = *(const bf16x8*)(sWr + ks * 2048 + (nt * 16 + r) * 32 + g * 8);
                #pragma unroll
                for (int mt = 0; mt < 2; ++mt) {
                    accCR[mt][nt] = MFMA16(aN[mt][ks], bC, accCR[mt][nt]);
                    accCR[mt][nt] = MFMA16(aE[mt][ks], bR, accCR[mt][nt]);
                }
            }
        }

        // ---- parent projection: accP[j-tile][d-tile] ----
        f32x4 accP[2][4];
        #pragma unroll
        for (int mt = 0; mt < 2; ++mt)
            #pragma unroll
            for (int nt = 0; nt < 4; ++nt) accP[mt][nt] = f32x4{0.f, 0.f, 0.f, 0.f};
        #pragma unroll
        for (int ks = 0; ks < 2; ++ks) {
            #pragma unroll
            for (int nt = 0; nt < 4; ++nt) {
                bf16x8 bW = *(const bf16x8*)(sWp + ks * 2048 + (nt * 16 + r) * 32 + g * 8);
                #pragma unroll
                for (int mt = 0; mt < 2; ++mt)
                    accP[mt][nt] = MFMA16(aN[mt][ks], bW, accP[mt][nt]);
            }
        }

        // ---- P (+b_parent on real rows) -> wave-private PT[d][k], packed b64 writes ----
        // rows j>=24 hold finite dup-row garbage; they land in PT k>=24 which the
        // aggregation multiplies by aA's zeroed k>=24 columns.
        #pragma unroll
        for (int mt = 0; mt < 2; ++mt) {
            const bool addb = (mt == 0) || (g < 2);   // j = mt*16+g*4+rr < 24
            #pragma unroll
            for (int nt = 0; nt < 4; ++nt) {
                us4 w;
                #pragma unroll
                for (int rr = 0; rr < 4; ++rr) {
                    float v = accP[mt][nt][rr];
                    if (addb) v += bpv[nt];
                    w[rr] = __builtin_bit_cast(unsigned short, (__bf16)v);
                }
                *(us4*)(myPT + (nt * 16 + r) * 32 + mt * 16 + g * 4) = w;
            }
        }

        // ---- aggregation: accA[j][d] = adjT x P, accumulated on top of accCR (MFMA C-in) ----
        f32x4 accA[2][4];
        #pragma unroll
        for (int nt = 0; nt < 4; ++nt) {
            bf16x8 bP = *(const bf16x8*)(myPT + (nt * 16 + r) * 32 + g * 8);
            #pragma unroll
            for (int mt = 0; mt < 2; ++mt)
                accA[mt][nt] = MFMA16(aA[mt], bP, accCR[mt][nt]);
        }

        // ---- epilogue: sigmoid((sum + b_child + b_rec)/3) ----
        #pragma unroll
        for (int mt = 0; mt < 2; ++mt) {
            #pragma unroll
            for (int rr = 0; rr < 4; ++rr) {
                const int j = mt * 16 + g * 4 + rr;
                if (j < JJ) {
                    float* op = out + (size_t)b * ROW + j * CC + r;
                    #pragma unroll
                    for (int nt = 0; nt < 4; ++nt) {
                        float x = (accA[mt][nt][rr] + bs[nt]) * (1.0f / 3.0f);
                        float s = __builtin_amdgcn_rcpf(1.0f + __expf(-x));
                        op[nt * 16] = s;
                    }
                }
            }
        }
    }
}

extern "C" void kernel_launch(void* const* d_in, const int* in_sizes, int n_in,
                              void* d_out, int out_size, void* d_ws, size_t ws_size,
                              hipStream_t stream) {
    const float* node = (const float*)d_in[0];
    const float* edge = (const float*)d_in[1];
    const float* adj  = (const float*)d_in[2];
    const float* Wp   = (const float*)d_in[3];
    const float* bpar = (const float*)d_in[4];
    const float* Wr   = (const float*)d_in[5];
    const float* brec = (const float*)d_in[6];
    const float* Wc   = (const float*)d_in[7];
    const float* bch  = (const float*)d_in[8];

    n2e_kernel<<<BLOCKS, 512, 0, stream>>>(node, edge, adj, Wp, bpar, Wr, brec, Wc, bch,
                                           (float*)d_out);
}

// Round 4
// 90.235 us; speedup vs baseline: 1.0293x; 1.0293x over previous
//
#include <hip/hip_runtime.h>
#include <hip/hip_bf16.h>

typedef __bf16 bf16x8 __attribute__((ext_vector_type(8)));
typedef float  f32x4  __attribute__((ext_vector_type(4)));
typedef unsigned short us4 __attribute__((ext_vector_type(4)));

#define MFMA16(a, b, c) __builtin_amdgcn_mfma_f32_16x16x32_bf16((a), (b), (c), 0, 0, 0)

constexpr int JJ     = 24;
constexpr int CC     = 64;
constexpr int ROW    = JJ * CC;    // 1536
constexpr int WAVES  = 8;          // 512 threads/block
constexpr int BPW    = 8;          // batches per wave
constexpr int BLOCKS = 16384 / (WAVES * BPW);   // 256 -> exactly 1 block/CU

struct Raw {                        // one batch's raw fp32 data, fully register-resident
    f32x4 n[2][2][2];               // node rows (r, 16+r'), 2 k-blocks, 2 halves
    f32x4 e[2][2][2];               // edge
    float a[2][8];                  // adj^T gather
};

__global__ __launch_bounds__(512, 2) void n2e_kernel(
    const float* __restrict__ node, const float* __restrict__ edge,
    const float* __restrict__ adj,
    const float* __restrict__ Wp, const float* __restrict__ bp,
    const float* __restrict__ Wr, const float* __restrict__ br,
    const float* __restrict__ Wc, const float* __restrict__ bc,
    float* __restrict__ out)
{
    __shared__ __bf16 sWc[2 * 64 * 32];     // k-blocked W^T: [ks][d][32]
    __shared__ __bf16 sWr[2 * 64 * 32];
    __shared__ __bf16 sWp[2 * 64 * 32];
    __shared__ float  sBsum[64];
    __shared__ float  sBpar[64];
    __shared__ __bf16 sPT[WAVES * 64 * 32]; // per-wave P^T[d][k]

    const int tid = threadIdx.x;

    for (int idx = tid; idx < 4096; idx += 512) {
        int c = idx >> 6, d = idx & 63;
        int dst = (c >> 5) * 2048 + d * 32 + (c & 31);
        sWc[dst] = (__bf16)Wc[idx];
        sWr[dst] = (__bf16)Wr[idx];
        sWp[dst] = (__bf16)Wp[idx];
    }
    if (tid < 64) { sBsum[tid] = bc[tid] + br[tid]; sBpar[tid] = bp[tid]; }
    __syncthreads();   // only block-wide barrier

    const int lane = tid & 63;
    const int wave = tid >> 6;
    const int r    = lane & 15;
    const int g    = lane >> 4;

    __bf16* myPT = sPT + wave * 2048;

    float bs[4], bpv[4];
    #pragma unroll
    for (int nt = 0; nt < 4; ++nt) { bs[nt] = sBsum[nt * 16 + r]; bpv[nt] = sBpar[nt * 16 + r]; }

    const int  row1s  = (16 + r < JJ) ? (16 + r) : r;   // safe dup row for j>=24 tail
    const bool adjval = (g < 3);                        // k-groups 0..2 real; g==3 zero pad

    // ---------------- pipelined stages ----------------
    auto LOAD = [&](Raw& R, int b) {
        const float* nf = node + (size_t)b * ROW;
        const float* ef = edge + (size_t)b * ROW;
        const float* af = adj  + (size_t)b * (JJ * JJ);
        #pragma unroll
        for (int mt = 0; mt < 2; ++mt) {
            const int rw = (mt == 0) ? r : row1s;
            const float* np = nf + rw * CC + g * 8;
            const float* ep = ef + rw * CC + g * 8;
            #pragma unroll
            for (int ks = 0; ks < 2; ++ks)
                #pragma unroll
                for (int h = 0; h < 2; ++h) {
                    R.n[mt][ks][h] = *(const f32x4*)(np + ks * 32 + h * 4);
                    R.e[mt][ks][h] = *(const f32x4*)(ep + ks * 32 + h * 4);
                }
        }
        #pragma unroll
        for (int mt = 0; mt < 2; ++mt) {
            const int j = mt * 16 + r;
            const bool v = adjval && (j < JJ);
            #pragma unroll
            for (int e = 0; e < 8; ++e) {
                const int idx = v ? ((g * 8 + e) * JJ + j) : 0;   // dup-safe, branchless
                R.a[mt][e] = af[idx];
            }
        }
    };

    auto COMPUTE = [&](Raw& R, int b) {
        // convert to MFMA fragments (frees R's raw regs)
        bf16x8 aN[2][2], aE[2][2];
        #pragma unroll
        for (int mt = 0; mt < 2; ++mt)
            #pragma unroll
            for (int ks = 0; ks < 2; ++ks) {
                bf16x8 an, ae;
                #pragma unroll
                for (int e = 0; e < 8; ++e) {
                    an[e] = (__bf16)R.n[mt][ks][e >> 2][e & 3];
                    ae[e] = (__bf16)R.e[mt][ks][e >> 2][e & 3];
                }
                aN[mt][ks] = an; aE[mt][ks] = ae;
            }
        bf16x8 aA[2];
        #pragma unroll
        for (int mt = 0; mt < 2; ++mt) {
            const int j = mt * 16 + r;
            const float m = (adjval && (j < JJ)) ? 1.0f : 0.0f;  // multiplier must be 0 in pads
            bf16x8 t;
            #pragma unroll
            for (int e = 0; e < 8; ++e) t[e] = (__bf16)(R.a[mt][e] * m);
            aA[mt] = t;
        }

        // children + recurrent
        f32x4 accCR[2][4];
        #pragma unroll
        for (int mt = 0; mt < 2; ++mt)
            #pragma unroll
            for (int nt = 0; nt < 4; ++nt) accCR[mt][nt] = f32x4{0.f, 0.f, 0.f, 0.f};
        #pragma unroll
        for (int ks = 0; ks < 2; ++ks) {
            #pragma unroll
            for (int nt = 0; nt < 4; ++nt) {
                bf16x8 bC = *(const bf16x8*)(sWc + ks * 2048 + (nt * 16 + r) * 32 + g * 8);
                bf16x8 bR = *(const bf16x8*)(sWr + ks * 2048 + (nt * 16 + r) * 32 + g * 8);
                #pragma unroll
                for (int mt = 0; mt < 2; ++mt) {
                    accCR[mt][nt] = MFMA16(aN[mt][ks], bC, accCR[mt][nt]);
                    accCR[mt][nt] = MFMA16(aE[mt][ks], bR, accCR[mt][nt]);
                }
            }
        }

        // parent projection
        f32x4 accP[2][4];
        #pragma unroll
        for (int mt = 0; mt < 2; ++mt)
            #pragma unroll
            for (int nt = 0; nt < 4; ++nt) accP[mt][nt] = f32x4{0.f, 0.f, 0.f, 0.f};
        #pragma unroll
        for (int ks = 0; ks < 2; ++ks) {
            #pragma unroll
            for (int nt = 0; nt < 4; ++nt) {
                bf16x8 bW = *(const bf16x8*)(sWp + ks * 2048 + (nt * 16 + r) * 32 + g * 8);
                #pragma unroll
                for (int mt = 0; mt < 2; ++mt)
                    accP[mt][nt] = MFMA16(aN[mt][ks], bW, accP[mt][nt]);
            }
        }

        // P (+b_parent on real rows) -> wave-private PT[d][k]
        #pragma unroll
        for (int mt = 0; mt < 2; ++mt) {
            const bool addb = (mt == 0) || (g < 2);   // j = mt*16+g*4+rr < 24
            #pragma unroll
            for (int nt = 0; nt < 4; ++nt) {
                us4 w;
                #pragma unroll
                for (int rr = 0; rr < 4; ++rr) {
                    float v = accP[mt][nt][rr];
                    if (addb) v += bpv[nt];
                    w[rr] = __builtin_bit_cast(unsigned short, (__bf16)v);
                }
                *(us4*)(myPT + (nt * 16 + r) * 32 + mt * 16 + g * 4) = w;
            }
        }

        // aggregation on top of accCR (MFMA C-in)
        f32x4 accA[2][4];
        #pragma unroll
        for (int nt = 0; nt < 4; ++nt) {
            bf16x8 bP = *(const bf16x8*)(myPT + (nt * 16 + r) * 32 + g * 8);
            #pragma unroll
            for (int mt = 0; mt < 2; ++mt)
                accA[mt][nt] = MFMA16(aA[mt], bP, accCR[mt][nt]);
        }

        // epilogue: sigmoid((sum + b_child + b_rec)/3)
        #pragma unroll
        for (int mt = 0; mt < 2; ++mt) {
            #pragma unroll
            for (int rr = 0; rr < 4; ++rr) {
                const int j = mt * 16 + g * 4 + rr;
                if (j < JJ) {
                    float* op = out + (size_t)b * ROW + j * CC + r;
                    #pragma unroll
                    for (int nt = 0; nt < 4; ++nt) {
                        float x = (accA[mt][nt][rr] + bs[nt]) * (1.0f / 3.0f);
                        float s = __builtin_amdgcn_rcpf(1.0f + __expf(-x));
                        op[nt * 16] = s;
                    }
                }
            }
        }
    };

    // ---------------- 2-deep pipeline over BPW batches ----------------
    const int wb = blockIdx.x * (WAVES * BPW) + wave * BPW;
    Raw A, B;
    LOAD(A, wb);
    for (int it = 0; it < BPW - 2; it += 2) {
        LOAD(B, wb + it + 1);
        COMPUTE(A, wb + it);
        LOAD(A, wb + it + 2);
        COMPUTE(B, wb + it + 1);
    }
    LOAD(B, wb + BPW - 1);
    COMPUTE(A, wb + BPW - 2);
    COMPUTE(B, wb + BPW - 1);
}

extern "C" void kernel_launch(void* const* d_in, const int* in_sizes, int n_in,
                              void* d_out, int out_size, void* d_ws, size_t ws_size,
                              hipStream_t stream) {
    const float* node = (const float*)d_in[0];
    const float* edge = (const float*)d_in[1];
    const float* adj  = (const float*)d_in[2];
    const float* Wp   = (const float*)d_in[3];
    const float* bpar = (const float*)d_in[4];
    const float* Wr   = (const float*)d_in[5];
    const float* brec = (const float*)d_in[6];
    const float* Wc   = (const float*)d_in[7];
    const float* bch  = (const float*)d_in[8];

    n2e_kernel<<<BLOCKS, 512, 0, stream>>>(node, edge, adj, Wp, bpar, Wr, brec, Wc, bch,
                                           (float*)d_out);
}